// Round 14
// baseline (3398.749 us; speedup 1.0000x reference)
//
#include <hip/hip_runtime.h>
#include <hip/hip_bf16.h>

static constexpr int T_  = 512;
static constexpr int B_  = 64;
static constexpr int I_  = 128;
static constexpr int H_  = 2048;
static constexpr int H1_ = 1024;
static constexpr int F2_ = 512;
static constexpr int H2_ = 256;
static constexpr int O_  = 64;
static constexpr int G1N = 4096;
static constexpr int G2N = 1024;
static constexpr int NW  = 176;   // worker blocks

typedef __attribute__((ext_vector_type(8))) __bf16 bfx8;
typedef __attribute__((ext_vector_type(4))) __bf16 bfx4;
typedef __attribute__((ext_vector_type(4))) float  fx4;

#define DEV __device__ __forceinline__

DEV fx4 mfma16(bfx8 a, bfx8 b, fx4 c) {
  return __builtin_amdgcn_mfma_f32_16x16x32_bf16(a, b, c, 0, 0, 0);
}
DEV float fast_sig(float x) { return 1.0f / (1.0f + __expf(-x)); }
DEV float fast_tanh(float x) {
  x = fminf(fmaxf(x, -30.0f), 30.0f);
  return 2.0f / (1.0f + __expf(-2.0f * x)) - 1.0f;
}
DEV float leaky_tanh_(float x) { return fast_tanh(x * (2.0f / 3.0f)) * 1.7159f + 0.01f * x; }

// ---- async global->LDS (16B/lane, dest uniform base + lane*16) ----
DEV void gld16(const void* g, void* l) {   // cached path
  __builtin_amdgcn_global_load_lds(
      (const __attribute__((address_space(1))) unsigned int*)g,
      (__attribute__((address_space(3))) unsigned int*)l, 16, 0, 0);
}
DEV void gld16c(const void* g, void* l) {  // coherent path (aux=17, bypass L1/L2)
  __builtin_amdgcn_global_load_lds(
      (const __attribute__((address_space(1))) unsigned int*)g,
      (__attribute__((address_space(3))) unsigned int*)l, 16, 0, 17);
}
DEV void spin_ge(int* p, int tgt) {
  while (__hip_atomic_load(p, __ATOMIC_RELAXED, __HIP_MEMORY_SCOPE_AGENT) < tgt)
    __builtin_amdgcn_s_sleep(1);
}
DEV void sstamp(int* p, int v) {   // relaxed agent store (fire-and-forget publish)
  __hip_atomic_store(p, v, __ATOMIC_RELAXED, __HIP_MEMORY_SCOPE_AGENT);
}
DEV void stc2(unsigned short* p, unsigned short v) {  // write-through 2B store
  __hip_atomic_store(p, v, __ATOMIC_RELAXED, __HIP_MEMORY_SCOPE_AGENT);
}
DEV unsigned long long ldc8(const void* p) {          // coherent 8B load
  return __hip_atomic_load((const unsigned long long*)p, __ATOMIC_RELAXED,
                           __HIP_MEMORY_SCOPE_AGENT);
}
DEV unsigned short bf16bits(float f) {
  __bf16 h = (__bf16)f;
  return __builtin_bit_cast(unsigned short, h);
}
DEV void arrive1(int* p) {   // caller must have __syncthreads()'d (drains stores)
  __hip_atomic_fetch_add(p, 1, __ATOMIC_RELAXED, __HIP_MEMORY_SCOPE_AGENT);
}

// ---- prep kernel: conversions + whh1 rearrange + bias sums + zeroing ----
struct PP {
  const float *fc1w, *wih1f, *whh1f, *fc2w, *wih2f, *whh2f, *fc3w, *fin;
  const float *bih1, *bhh1, *bih2, *bhh2;
  __bf16 *wb_fc1, *wb_ih1, *W2, *wb_fc2, *wb_ih2, *wb_hh2, *wb_fc3, *in_bf;
  float *bsum1, *bsum2, *c1, *c2;
  __bf16 *h1zero, *h2a;
};
__global__ void k_prep(PP q) {
  const int bid = blockIdx.x, tid = threadIdx.x;
  if (bid < 2048) {
    // whh1 fp32[4096][1024] -> W2 bf16 streaming layout
    int v = bid * 256 + tid;
    int l = v & 63, kk = (v >> 6) & 31, g = (v >> 11) & 3, ng = v >> 13;
    int row = g * 1024 + ng * 16 + (l & 15);
    int k0  = kk * 32 + (l >> 4) * 8;
    const float* sp = q.whh1f + (size_t)row * 1024 + k0;
    float4 v0 = ((const float4*)sp)[0];
    float4 v1 = ((const float4*)sp)[1];
    bfx8 o = { (__bf16)v0.x, (__bf16)v0.y, (__bf16)v0.z, (__bf16)v0.w,
               (__bf16)v1.x, (__bf16)v1.y, (__bf16)v1.z, (__bf16)v1.w };
    *(bfx8*)(q.W2 + (size_t)v * 8) = o;
    return;
  }
  const int gw = (bid - 2048) * 256 + tid, gs = 512 * 256;
  for (int i = gw; i < 65536; i += gs) q.c1[i] = 0.0f;
  for (int i = gw; i < 16384; i += gs) q.c2[i] = 0.0f;
  for (int i = gw; i < 32768; i += gs) ((unsigned*)q.h1zero)[i] = 0u;
  for (int i = gw; i < 8192;  i += gs) ((unsigned*)q.h2a)[i] = 0u;
  for (int i = gw; i < 4096; i += gs) q.bsum1[i] = q.bih1[i] + q.bhh1[i];
  for (int i = gw; i < 1024; i += gs) q.bsum2[i] = q.bih2[i] + q.bhh2[i];
  auto cv = [&](const float* s, __bf16* d, int n4) {
    for (int i = gw; i < n4; i += gs) {
      float4 v = ((const float4*)s)[i];
      bfx4 o = { (__bf16)v.x, (__bf16)v.y, (__bf16)v.z, (__bf16)v.w };
      ((bfx4*)d)[i] = o;
    }
  };
  cv(q.fc1w,  q.wb_fc1, (H_ * I_) / 4);
  cv(q.wih1f, q.wb_ih1, (G1N * H_) / 4);
  cv(q.fc2w,  q.wb_fc2, (F2_ * H1_) / 4);
  cv(q.wih2f, q.wb_ih2, (G2N * F2_) / 4);
  cv(q.whh2f, q.wb_hh2, (G2N * H2_) / 4);
  cv(q.fc3w,  q.wb_fc3, (O_ * H2_) / 4);
  cv(q.fin,   q.in_bf,  (T_ * B_ * I_) / 4);
}

// ---- GEMM tile 128x128, BK=64, global_load_lds staging, swizzled LDS (round-8 proven) ----
// epi 1: leaky_tanh; wt 1: write-through stc2 stores
DEV void gemm_tile(char* sm, const __bf16* __restrict__ A, const __bf16* __restrict__ W,
                   __bf16* __restrict__ outB, const float* __restrict__ bias,
                   int m0, int n0, int N, int K, int epi, int wt)
{
  char* As = sm;            // [128][128B] 16KB, granule (r,p) holds global (r, p^(r&7))
  char* Ws = sm + 16384;    // 16KB
  const int tid = threadIdx.x, lane = tid & 63, wave = tid >> 6;
  const int wm = wave >> 1, wn = wave & 1;
  const int rr = lane & 15, hi = lane >> 4;
  fx4 acc[4][4] = {};
  for (int k0 = 0; k0 < K; k0 += 64) {
    __syncthreads();
#pragma unroll
    for (int i = 0; i < 4; ++i) {
      int idx = i * 256 + tid;
      int r = idx >> 3, cs = (idx & 7) ^ (r & 7);
      gld16(A + (size_t)(m0 + r) * K + k0 + cs * 8, As + idx * 16);
      gld16(W + (size_t)(n0 + r) * K + k0 + cs * 8, Ws + idx * 16);
    }
    __syncthreads();   // drains DMA
#pragma unroll
    for (int kh = 0; kh < 2; ++kh) {
      bfx8 a[4], b[4];
      const int cg = kh * 4 + hi;
#pragma unroll
      for (int mi = 0; mi < 4; ++mi) {
        int ra = wm * 64 + mi * 16 + rr;
        a[mi] = *(const bfx8*)(As + ra * 128 + ((cg ^ (ra & 7)) << 4));
      }
#pragma unroll
      for (int ni = 0; ni < 4; ++ni) {
        int rb = wn * 64 + ni * 16 + rr;
        b[ni] = *(const bfx8*)(Ws + rb * 128 + ((cg ^ (rb & 7)) << 4));
      }
#pragma unroll
      for (int mi = 0; mi < 4; ++mi)
#pragma unroll
        for (int ni = 0; ni < 4; ++ni)
          acc[mi][ni] = mfma16(a[mi], b[ni], acc[mi][ni]);
    }
  }
  const int cr = hi * 4, cc = rr;
#pragma unroll
  for (int mi = 0; mi < 4; ++mi)
#pragma unroll
    for (int ni = 0; ni < 4; ++ni) {
      int col = n0 + wn * 64 + ni * 16 + cc;
#pragma unroll
      for (int r = 0; r < 4; ++r) {
        int row = m0 + wm * 64 + mi * 16 + cr + r;
        float v = acc[mi][ni][r] + bias[col];
        if (epi == 1) v = leaky_tanh_(v);
        if (wt) stc2((unsigned short*)outB + ((size_t)row * N + col), bf16bits(v));
        else    outB[(size_t)row * N + col] = (__bf16)v;
      }
    }
}

// ---- standalone GEMM (prologue) ----
__launch_bounds__(256)
__global__ void k_gemm(const __bf16* __restrict__ A, const __bf16* __restrict__ W,
                       __bf16* __restrict__ outB, const float* __restrict__ bias,
                       int M, int N, int K, int epi)
{
  __shared__ __align__(16) char sm[32768];
  (void)M;
  gemm_tile(sm, A, W, outB, bias, blockIdx.y * 128, blockIdx.x * 128, N, K, epi, 0);
}

// ---- LDS stage helper (XOR-swizzled 16B chunks), plain cached loads ----
DEV void stage(char* dst, int rsB, const __bf16* __restrict__ src, size_t sStride,
               int n, int lg) {
  for (int idx = threadIdx.x; idx < n; idx += 256) {
    int r = idx >> lg, c = idx & ((1 << lg) - 1);
    *(bfx8*)(dst + r * rsB + ((c * 16) ^ ((r & 7) << 4))) =
        *(const bfx8*)(src + (size_t)r * sStride + c * 8);
  }
}

// ---- fused persistent kernel params ----
struct KP {
  const __bf16 *W2, *whh2b;
  const __bf16 *g1rd;  __bf16 *g1wr;
  const __bf16 *xcrd;  __bf16 *xcwr;
  const __bf16 *infc1;
  const __bf16 *h1rd;  const __bf16 *h1s0;  __bf16 *h1wr;
  __bf16 *x2c; __bf16 *g2;
  const __bf16 *wfc1, *wih1, *wfc2, *wih2;
  const float *bfc1, *bs1, *bfc2, *bs2;
  float *c1, *c2;
  __bf16 *h2a;
  int *cnt;
  int Tc, t2base, do_l1, do_l2, do_fc2, do_ih1, do_fc1;
};

// grid 256: [0,64) LSTM1(chunk k) | [64,80) LSTM2(chunk k-1) | [80,256) workers
// sync (zeroed per launch):
//  h1 stamps: cnt[768+b] (b=0..63), producer b stores s+1 after writing h1 slot s+1
//  h2 stamps: cnt[896+b] (b=0..15)
//  worker gates (once/launch, fetch_add): cnt[576] fc2-done, cnt[640] ih2-done
__launch_bounds__(256, 1)
__global__ void k_persist3(KP p)
{
  __shared__ __align__(16) char smem[131072];
  const int tid = threadIdx.x, lane = tid & 63, wv = tid >> 6;
  const int rr = lane & 15, hi = lane >> 4;
  const int col = tid & 15, brow = tid >> 4;
  const int bid = blockIdx.x;
  int* cnt = p.cnt;
  const int Tc = p.Tc;

  if (bid < 64) {
    // ======== LSTM1 (round-8 core; stamp-based handshake) ========
    if (!p.do_l1) return;
    const int ng = bid;
    char* As = smem;
    float* Cp = (float*)smem;

    bfx8 wreg[4][8];
#pragma unroll
    for (int g = 0; g < 4; ++g)
#pragma unroll
      for (int j = 0; j < 8; ++j)
        wreg[g][j] = *(const bfx8*)(p.W2 + (size_t)((ng * 4 + g) * 32 + wv * 8 + j) * 512 + lane * 8);

    float pc[4];
#pragma unroll
    for (int q = 0; q < 4; ++q)
      pc[q] = p.c1[(brow + q * 16) * 1024 + ng * 16 + col];

    for (int s = 0; s < Tc; ++s) {
      float pg[4][4];
#pragma unroll
      for (int q = 0; q < 4; ++q)
#pragma unroll
        for (int g = 0; g < 4; ++g)
          pg[q][g] = (float)p.g1rd[(size_t)(s * 64 + brow + q * 16) * 4096 + g * 1024 + ng * 16 + col];

      if (s > 0 && wv == 0) spin_ge(cnt + 768 + lane, s);   // 64 stamps, 1 lane each
      __syncthreads();

      const __bf16* h1s = (s == 0) ? p.h1s0 : (p.h1wr + (size_t)s * 65536);
      {
        char* dstb = smem + wv * 32768;
#pragma unroll 8
        for (int i = 0; i < 32; ++i) {
          int d = wv * 2048 + i * 64 + lane;
          int r = d >> 7;
          int sg = (r << 7) | ((d & 127) ^ (r & 7));
          gld16c(h1s + (size_t)sg * 8, dstb + i * 1024);
        }
      }
      __syncthreads();

      fx4 acc[4][4] = {};
#pragma unroll
      for (int j = 0; j < 8; ++j) {
        const int kB = (wv * 8 + j) * 64 + hi * 16;
        bfx8 a[4];
#pragma unroll
        for (int m = 0; m < 4; ++m) {
          int ra = m * 16 + rr;
          a[m] = *(const bfx8*)(As + ra * 2048 + (kB ^ ((ra & 7) << 4)));
        }
#pragma unroll
        for (int g = 0; g < 4; ++g)
#pragma unroll
          for (int m = 0; m < 4; ++m)
            acc[g][m] = mfma16(a[m], wreg[g][j], acc[g][m]);
      }
      __syncthreads();
#pragma unroll
      for (int g = 0; g < 4; ++g)
#pragma unroll
        for (int m = 0; m < 4; ++m) {
          int gc = g * 16 + rr;
          int bx = (m * 16 + hi * 4) ^ ((gc & 15) << 2);
          *(fx4*)(Cp + ((wv * 64 + gc) * 64 + bx)) = acc[g][m];
        }
      __syncthreads();

      __bf16* h1o = p.h1wr + (size_t)(s + 1) * 65536;
#pragma unroll
      for (int q = 0; q < 4; ++q) {
        int b_ = brow + q * 16;
        float gv[4];
#pragma unroll
        for (int g = 0; g < 4; ++g) {
          int gc = g * 16 + col;
          int bx = b_ ^ ((gc & 15) << 2);
          float v = pg[q][g];
#pragma unroll
          for (int w = 0; w < 4; ++w)
            v += Cp[(w * 64 + gc) * 64 + bx];
          gv[g] = v;
        }
        float cn = fast_sig(gv[1]) * pc[q] + fast_sig(gv[0]) * fast_tanh(gv[2]);
        pc[q] = cn;
        float hv = fast_sig(gv[3]) * fast_tanh(cn);
        stc2((unsigned short*)h1o + (b_ * 1024 + ng * 16 + col), bf16bits(hv));
      }
      __syncthreads();   // drains write-through stores before publish
      if (tid == 0) sstamp(cnt + 768 + ng, s + 1);
    }
#pragma unroll
    for (int q = 0; q < 4; ++q)
      p.c1[(brow + q * 16) * 1024 + ng * 16 + col] = pc[q];

  } else if (bid < 80) {
    // ======== LSTM2 (chunk k-1; stamp-based handshake) ========
    if (!p.do_l2) return;
    const int ng2 = bid - 64;
    char* Ws2 = smem;
    char* As2 = smem + 32768;
    float (*Gx2)[64][16] = (float (*)[64][16])(smem + 32768);

    for (int idx = tid; idx < 2048; idx += 256) {
      int r = idx >> 5, c = idx & 31;
      int wr = (r >> 4) * 256 + ng2 * 16 + (r & 15);
      *(bfx8*)(Ws2 + r * 512 + ((c * 16) ^ ((r & 7) << 4))) =
          *(const bfx8*)(p.whh2b + (size_t)wr * 256 + c * 8);
    }
    float pc2[4];
#pragma unroll
    for (int q = 0; q < 4; ++q)
      pc2[q] = p.c2[(brow + q * 16) * 256 + ng2 * 16 + col];

    // wait until workers finished ih2 (G2 ready, write-through + released)
    if (tid == 0) spin_ge(cnt + 640, NW);
    __syncthreads();

    for (int s = 0; s < Tc; ++s) {
      float pg[4][4];
#pragma unroll
      for (int q = 0; q < 4; ++q)
#pragma unroll
        for (int g = 0; g < 4; ++g)
          pg[q][g] = (float)p.g2[(size_t)(s * 64 + brow + q * 16) * 1024 + g * 256 + ng2 * 16 + col];

      if (s > 0 && wv == 0 && lane < 16) spin_ge(cnt + 896 + lane, s);
      __syncthreads();

      const __bf16* h2s = p.h2a + (size_t)(p.t2base + s) * 16384;
      for (int idx = tid; idx < 2048; idx += 256) {
        int r = idx >> 5, c = idx & 31;
        const char* sp = (const char*)(h2s + r * 256 + c * 8);
        unsigned long long lo = ldc8(sp), hi8 = ldc8(sp + 8);
        char* dp = As2 + r * 512 + ((c * 16) ^ ((r & 7) << 4));
        *(unsigned long long*)dp = lo;
        *(unsigned long long*)(dp + 8) = hi8;
      }
      __syncthreads();

      fx4 acc[4] = {};
#pragma unroll
      for (int ks = 0; ks < 8; ++ks) {
        const int cb = ks * 64 + hi * 16;
        int rb = wv * 16 + rr;
        bfx8 bfr = *(const bfx8*)(Ws2 + rb * 512 + (cb ^ ((rb & 7) << 4)));
#pragma unroll
        for (int m = 0; m < 4; ++m) {
          int ra = m * 16 + rr;
          bfx8 afr = *(const bfx8*)(As2 + ra * 512 + (cb ^ ((ra & 7) << 4)));
          acc[m] = mfma16(afr, bfr, acc[m]);
        }
      }
      __syncthreads();
#pragma unroll
      for (int m = 0; m < 4; ++m)
#pragma unroll
        for (int r = 0; r < 4; ++r)
          Gx2[wv][m * 16 + hi * 4 + r][rr] = acc[m][r];
      __syncthreads();

      __bf16* h2o = p.h2a + (size_t)(p.t2base + s + 1) * 16384;
#pragma unroll
      for (int q = 0; q < 4; ++q) {
        int b_ = brow + q * 16;
        float gi = Gx2[0][b_][col] + pg[q][0];
        float gf = Gx2[1][b_][col] + pg[q][1];
        float gg = Gx2[2][b_][col] + pg[q][2];
        float go = Gx2[3][b_][col] + pg[q][3];
        float cn = fast_sig(gf) * pc2[q] + fast_sig(gi) * fast_tanh(gg);
        pc2[q] = cn;
        float hv = fast_sig(go) * fast_tanh(cn);
        stc2((unsigned short*)h2o + (b_ * 256 + ng2 * 16 + col), bf16bits(hv));
      }
      __syncthreads();
      if (tid == 0) sstamp(cnt + 896 + ng2, s + 1);
    }
#pragma unroll
    for (int q = 0; q < 4; ++q)
      p.c2[(brow + q * 16) * 256 + ng2 * 16 + col] = pc2[q];

  } else {
    // ======== workers ========
    const int wid = bid - 80;
    const int Mt = (Tc * 64) / 128;
    if (p.do_fc2) {
      // fc2(k-1): x2 = leaky(h1 @ wfc2^T + b)   [h1 from last launch, plain]
      for (int i = wid; i < Mt * 4; i += NW)
        gemm_tile(smem, p.h1rd + 65536, p.wfc2, p.x2c, p.bfc2,
                  (i >> 2) * 128, (i & 3) * 128, F2_, H1_, 1, 1);
      __syncthreads();
      if (tid == 0) { arrive1(cnt + 576); spin_ge(cnt + 576, NW); }
      __syncthreads();
      // ih2(k-1): G2 = x2 @ wih2^T + bs2   [x2 same-launch write-through]
      for (int i = wid; i < Mt * 8; i += NW)
        gemm_tile(smem, p.x2c, p.wih2, p.g2, p.bs2,
                  (i >> 3) * 128, (i & 7) * 128, G2N, F2_, 0, 1);
      __syncthreads();
      if (tid == 0) arrive1(cnt + 640);
    }
    if (p.do_ih1) {
      // ih1(k+1): G1 = Xc @ wih1^T + bs1   [Xc from last launch, plain]
      for (int i = wid; i < Mt * 32; i += NW)
        gemm_tile(smem, p.xcrd, p.wih1, p.g1wr, p.bs1,
                  (i >> 5) * 128, (i & 31) * 128, G1N, H_, 0, 0);
    }
    if (p.do_fc1) {
      // fc1(k+2): Xc = leaky(in @ wfc1^T + b)
      for (int i = wid; i < Mt * 16; i += NW)
        gemm_tile(smem, p.infc1, p.wfc1, p.xcwr, p.bfc1,
                  (i >> 4) * 128, (i & 15) * 128, H_, I_, 1, 0);
    }
  }
}

// ---- fc3 over all timesteps ----
__launch_bounds__(256)
__global__ void k_fc3b(const __bf16* __restrict__ H2mat, const __bf16* __restrict__ w3,
                       const float* __restrict__ b3, float* __restrict__ out)
{
  __shared__ __align__(16) char smem[65536];
  const int tid = threadIdx.x, lane = tid & 63, wv = tid >> 6;
  const int rr = lane & 15, hi = lane >> 4;
  char* As = smem;
  char* Ws = smem + 32768;
  const size_t row0 = (size_t)blockIdx.x * 64;
  stage(As, 512, H2mat + row0 * 256, 256, 2048, 5);
  stage(Ws, 512, w3, 256, 2048, 5);
  __syncthreads();
  fx4 acc[4] = {};
#pragma unroll
  for (int ks = 0; ks < 8; ++ks) {
    const int cbB = ks * 64 + hi * 16;
    int rb = wv * 16 + rr;
    bfx8 bfr = *(const bfx8*)(Ws + rb * 512 + (cbB ^ ((rb & 7) << 4)));
#pragma unroll
    for (int m = 0; m < 4; ++m) {
      int ra = m * 16 + rr;
      bfx8 afr = *(const bfx8*)(As + ra * 512 + (cbB ^ ((ra & 7) << 4)));
      acc[m] = mfma16(afr, bfr, acc[m]);
    }
  }
  float bv = b3[wv * 16 + rr];
#pragma unroll
  for (int m = 0; m < 4; ++m)
#pragma unroll
    for (int r = 0; r < 4; ++r)
      out[(row0 + m * 16 + hi * 4 + r) * 64 + wv * 16 + rr] = acc[m][r] + bv;
}

// ---------------- host launcher ----------------
extern "C" void kernel_launch(void* const* d_in, const int* in_sizes, int n_in,
                              void* d_out, int out_size, void* d_ws, size_t ws_size,
                              hipStream_t stream)
{
  (void)in_sizes; (void)n_in; (void)out_size;
  const float* f_in = (const float*)d_in[0];
  const float* fc1w = (const float*)d_in[1];
  const float* fc1b = (const float*)d_in[2];
  const float* wih1 = (const float*)d_in[3];
  const float* whh1 = (const float*)d_in[4];
  const float* bih1 = (const float*)d_in[5];
  const float* bhh1 = (const float*)d_in[6];
  const float* fc2w = (const float*)d_in[7];
  const float* fc2b = (const float*)d_in[8];
  const float* wih2 = (const float*)d_in[9];
  const float* whh2 = (const float*)d_in[10];
  const float* bih2 = (const float*)d_in[11];
  const float* bhh2 = (const float*)d_in[12];
  const float* fc3w = (const float*)d_in[13];
  const float* fc3b = (const float*)d_in[14];
  float* out = (float*)d_out;

  char* base = (char*)d_ws;
  size_t off = 0;
  auto alloc = [&](size_t bytes) -> char* {
    char* q = base + off;
    off = (off + bytes + 255) & ~(size_t)255;
    return q;
  };
  // fixed region
  __bf16* wb_fc1 = (__bf16*)alloc((size_t)H_ * I_ * 2);
  __bf16* wb_ih1 = (__bf16*)alloc((size_t)G1N * H_ * 2);
  __bf16* W2     = (__bf16*)alloc((size_t)G1N * H1_ * 2);
  __bf16* wb_fc2 = (__bf16*)alloc((size_t)F2_ * H1_ * 2);
  __bf16* wb_ih2 = (__bf16*)alloc((size_t)G2N * F2_ * 2);
  __bf16* wb_hh2 = (__bf16*)alloc((size_t)G2N * H2_ * 2);
  __bf16* wb_fc3 = (__bf16*)alloc((size_t)O_ * H2_ * 2);
  __bf16* in_bf  = (__bf16*)alloc((size_t)T_ * B_ * I_ * 2);
  float*  bsum1  = (float*) alloc((size_t)G1N * 4);
  float*  bsum2  = (float*) alloc((size_t)G2N * 4);
  float*  c1     = (float*) alloc((size_t)B_ * H1_ * 4);
  float*  c2     = (float*) alloc((size_t)B_ * H2_ * 4);
  __bf16* h2a    = (__bf16*)alloc((size_t)(T_ + 1) * B_ * H2_ * 2);
  __bf16* h1zero = (__bf16*)alloc((size_t)B_ * H1_ * 2);
  int*    cnt    = (int*)   alloc(4096);
  size_t fixed = off;

  auto perTc = [](size_t Tc) -> size_t {
    size_t Mc = Tc * 64;
    return 2 * Mc * H_ * 2      // Xc A/B
         + 2 * Mc * G1N * 2     // G1 A/B (bf16)
         + 2 * (Tc + 1) * (size_t)B_ * H1_ * 2   // h1 rings
         + Mc * F2_ * 2         // x2c
         + Mc * G2N * 2         // G2 (bf16)
         + 10 * 256;
  };
  int Tc = 128;
  while (Tc > 8 && fixed + perTc(Tc) > ws_size) Tc >>= 1;
  const int Mc = Tc * 64;
  __bf16* XcA  = (__bf16*)alloc((size_t)Mc * H_ * 2);
  __bf16* XcB  = (__bf16*)alloc((size_t)Mc * H_ * 2);
  __bf16* G1A  = (__bf16*)alloc((size_t)Mc * G1N * 2);
  __bf16* G1B  = (__bf16*)alloc((size_t)Mc * G1N * 2);
  __bf16* h1rA = (__bf16*)alloc((size_t)(Tc + 1) * B_ * H1_ * 2);
  __bf16* h1rB = (__bf16*)alloc((size_t)(Tc + 1) * B_ * H1_ * 2);
  __bf16* x2c  = (__bf16*)alloc((size_t)Mc * F2_ * 2);
  __bf16* G2cb = (__bf16*)alloc((size_t)Mc * G2N * 2);

  // ---- launch 1: prep (conversions + rearrange + zero) ----
  PP q;
  q.fc1w = fc1w; q.wih1f = wih1; q.whh1f = whh1; q.fc2w = fc2w;
  q.wih2f = wih2; q.whh2f = whh2; q.fc3w = fc3w; q.fin = f_in;
  q.bih1 = bih1; q.bhh1 = bhh1; q.bih2 = bih2; q.bhh2 = bhh2;
  q.wb_fc1 = wb_fc1; q.wb_ih1 = wb_ih1; q.W2 = W2; q.wb_fc2 = wb_fc2;
  q.wb_ih2 = wb_ih2; q.wb_hh2 = wb_hh2; q.wb_fc3 = wb_fc3; q.in_bf = in_bf;
  q.bsum1 = bsum1; q.bsum2 = bsum2; q.c1 = c1; q.c2 = c2;
  q.h1zero = h1zero; q.h2a = h2a;
  k_prep<<<2560, 256, 0, stream>>>(q);

  const int chunks = T_ / Tc;
  // ---- launch 2: fc1 for chunks 0+1 fused (XcA|XcB contiguous) ----
  k_gemm<<<dim3(H_ / 128, (2 * Mc) / 128), 256, 0, stream>>>(
      in_bf, wb_fc1, XcA, fc1b, 2 * Mc, H_, I_, 1);
  // ---- launch 3: ih1(0) -> G1A ----
  k_gemm<<<dim3(G1N / 128, Mc / 128), 256, 0, stream>>>(
      XcA, wb_ih1, G1A, bsum1, Mc, G1N, H_, 0);

  KP p;
  p.W2 = W2; p.whh2b = wb_hh2;
  p.wfc1 = wb_fc1; p.wih1 = wb_ih1; p.wfc2 = wb_fc2; p.wih2 = wb_ih2;
  p.bfc1 = fc1b; p.bs1 = bsum1; p.bfc2 = fc2b; p.bs2 = bsum2;
  p.c1 = c1; p.c2 = c2; p.h2a = h2a; p.cnt = cnt;
  p.x2c = x2c; p.g2 = G2cb; p.Tc = Tc;

  for (int k = 0; k < chunks; ++k) {
    hipMemsetAsync(cnt, 0, 4096, stream);
    p.g1rd = (k & 1) ? G1B : G1A;
    p.g1wr = (k & 1) ? G1A : G1B;
    p.xcrd = ((k + 1) & 1) ? XcB : XcA;
    p.xcwr = (k & 1) ? XcB : XcA;
    p.infc1 = (k + 2 < chunks) ? (in_bf + (size_t)(k + 2) * Mc * I_) : in_bf;
    p.h1wr = (k & 1) ? h1rB : h1rA;
    p.h1rd = (k & 1) ? h1rA : h1rB;
    p.h1s0 = (k == 0) ? h1zero : (p.h1rd + (size_t)Tc * 65536);
    p.t2base = (k - 1) * Tc;
    p.do_l1 = 1;
    p.do_l2 = (k >= 1);
    p.do_fc2 = (k >= 1);
    p.do_ih1 = (k + 1 < chunks);
    p.do_fc1 = (k + 2 < chunks);
    k_persist3<<<256, 256, 0, stream>>>(p);
  }
  // tail: fc2/ih2(chunks-1) + LSTM2(chunks-1)
  hipMemsetAsync(cnt, 0, 4096, stream);
  p.h1rd = ((chunks - 1) & 1) ? h1rB : h1rA;
  p.h1wr = (p.h1rd == h1rA) ? h1rB : h1rA;   // unused
  p.h1s0 = h1zero;                            // unused
  p.g1rd = G1A; p.g1wr = G1B; p.xcrd = XcA; p.xcwr = XcB; p.infc1 = in_bf;  // unused
  p.t2base = (chunks - 1) * Tc;
  p.do_l1 = 0; p.do_l2 = 1; p.do_fc2 = 1; p.do_ih1 = 0; p.do_fc1 = 0;
  k_persist3<<<256, 256, 0, stream>>>(p);
  // fc3 over all t
  k_fc3b<<<(T_ * B_) / 64, 256, 0, stream>>>(h2a + (size_t)B_ * H2_, wb_fc3, fc3b, out);
}

// Round 15
// 3328.574 us; speedup vs baseline: 1.0211x; 1.0211x over previous
//
#include <hip/hip_runtime.h>
#include <hip/hip_bf16.h>

static constexpr int T_  = 512;
static constexpr int B_  = 64;
static constexpr int I_  = 128;
static constexpr int H_  = 2048;
static constexpr int H1_ = 1024;
static constexpr int F2_ = 512;
static constexpr int H2_ = 256;
static constexpr int O_  = 64;
static constexpr int G1N = 4096;
static constexpr int G2N = 1024;
static constexpr int NW  = 176;   // worker blocks

typedef __attribute__((ext_vector_type(8))) __bf16 bfx8;
typedef __attribute__((ext_vector_type(4))) __bf16 bfx4;
typedef __attribute__((ext_vector_type(4))) float  fx4;

#define DEV __device__ __forceinline__

DEV fx4 mfma16(bfx8 a, bfx8 b, fx4 c) {
  return __builtin_amdgcn_mfma_f32_16x16x32_bf16(a, b, c, 0, 0, 0);
}
DEV float fast_sig(float x) { return 1.0f / (1.0f + __expf(-x)); }
DEV float fast_tanh(float x) {
  x = fminf(fmaxf(x, -30.0f), 30.0f);
  return 2.0f / (1.0f + __expf(-2.0f * x)) - 1.0f;
}
DEV float leaky_tanh_(float x) { return fast_tanh(x * (2.0f / 3.0f)) * 1.7159f + 0.01f * x; }

// ---- async global->LDS (16B/lane, dest uniform base + lane*16) ----
DEV void gld16(const void* g, void* l) {   // cached path
  __builtin_amdgcn_global_load_lds(
      (const __attribute__((address_space(1))) unsigned int*)g,
      (__attribute__((address_space(3))) unsigned int*)l, 16, 0, 0);
}
DEV void gld16c(const void* g, void* l) {  // coherent path (aux=17, bypass L1/L2)
  __builtin_amdgcn_global_load_lds(
      (const __attribute__((address_space(1))) unsigned int*)g,
      (__attribute__((address_space(3))) unsigned int*)l, 16, 0, 17);
}
DEV void spin_ge(int* p, int tgt) {
  while (__hip_atomic_load(p, __ATOMIC_RELAXED, __HIP_MEMORY_SCOPE_AGENT) < tgt)
    __builtin_amdgcn_s_sleep(1);
}
DEV void stc2(unsigned short* p, unsigned short v) {  // write-through 2B store
  __hip_atomic_store(p, v, __ATOMIC_RELAXED, __HIP_MEMORY_SCOPE_AGENT);
}
DEV unsigned long long ldc8(const void* p) {          // coherent 8B load
  return __hip_atomic_load((const unsigned long long*)p, __ATOMIC_RELAXED,
                           __HIP_MEMORY_SCOPE_AGENT);
}
DEV unsigned short bf16bits(float f) {
  __bf16 h = (__bf16)f;
  return __builtin_bit_cast(unsigned short, h);
}
DEV void arrive1(int* p) {   // caller must have __syncthreads()'d (drains stores)
  __hip_atomic_fetch_add(p, 1, __ATOMIC_RELAXED, __HIP_MEMORY_SCOPE_AGENT);
}

// ---- prep kernel: conversions + whh1 rearrange + bias sums + zeroing ----
struct PP {
  const float *fc1w, *wih1f, *whh1f, *fc2w, *wih2f, *whh2f, *fc3w, *fin;
  const float *bih1, *bhh1, *bih2, *bhh2;
  __bf16 *wb_fc1, *wb_ih1, *W2, *wb_fc2, *wb_ih2, *wb_hh2, *wb_fc3, *in_bf;
  float *bsum1, *bsum2, *c1, *c2;
  __bf16 *h1zero, *h2a;
};
__global__ void k_prep(PP q) {
  const int bid = blockIdx.x, tid = threadIdx.x;
  if (bid < 2048) {
    // whh1 fp32[4096][1024] -> W2 bf16 streaming layout
    int v = bid * 256 + tid;
    int l = v & 63, kk = (v >> 6) & 31, g = (v >> 11) & 3, ng = v >> 13;
    int row = g * 1024 + ng * 16 + (l & 15);
    int k0  = kk * 32 + (l >> 4) * 8;
    const float* sp = q.whh1f + (size_t)row * 1024 + k0;
    float4 v0 = ((const float4*)sp)[0];
    float4 v1 = ((const float4*)sp)[1];
    bfx8 o = { (__bf16)v0.x, (__bf16)v0.y, (__bf16)v0.z, (__bf16)v0.w,
               (__bf16)v1.x, (__bf16)v1.y, (__bf16)v1.z, (__bf16)v1.w };
    *(bfx8*)(q.W2 + (size_t)v * 8) = o;
    return;
  }
  const int gw = (bid - 2048) * 256 + tid, gs = 512 * 256;
  for (int i = gw; i < 65536; i += gs) q.c1[i] = 0.0f;
  for (int i = gw; i < 16384; i += gs) q.c2[i] = 0.0f;
  for (int i = gw; i < 32768; i += gs) ((unsigned*)q.h1zero)[i] = 0u;
  for (int i = gw; i < 8192;  i += gs) ((unsigned*)q.h2a)[i] = 0u;
  for (int i = gw; i < 4096; i += gs) q.bsum1[i] = q.bih1[i] + q.bhh1[i];
  for (int i = gw; i < 1024; i += gs) q.bsum2[i] = q.bih2[i] + q.bhh2[i];
  auto cv = [&](const float* s, __bf16* d, int n4) {
    for (int i = gw; i < n4; i += gs) {
      float4 v = ((const float4*)s)[i];
      bfx4 o = { (__bf16)v.x, (__bf16)v.y, (__bf16)v.z, (__bf16)v.w };
      ((bfx4*)d)[i] = o;
    }
  };
  cv(q.fc1w,  q.wb_fc1, (H_ * I_) / 4);
  cv(q.wih1f, q.wb_ih1, (G1N * H_) / 4);
  cv(q.fc2w,  q.wb_fc2, (F2_ * H1_) / 4);
  cv(q.wih2f, q.wb_ih2, (G2N * F2_) / 4);
  cv(q.whh2f, q.wb_hh2, (G2N * H2_) / 4);
  cv(q.fc3w,  q.wb_fc3, (O_ * H2_) / 4);
  cv(q.fin,   q.in_bf,  (T_ * B_ * I_) / 4);
}

// ---- GEMM tile 128x128, BK=64, global_load_lds staging, swizzled LDS (round-8 proven) ----
// epi 1: leaky_tanh; wt 1: write-through stc2 stores
DEV void gemm_tile(char* sm, const __bf16* __restrict__ A, const __bf16* __restrict__ W,
                   __bf16* __restrict__ outB, const float* __restrict__ bias,
                   int m0, int n0, int N, int K, int epi, int wt)
{
  char* As = sm;            // [128][128B] 16KB, granule (r,p) holds global (r, p^(r&7))
  char* Ws = sm + 16384;    // 16KB
  const int tid = threadIdx.x, lane = tid & 63, wave = tid >> 6;
  const int wm = wave >> 1, wn = wave & 1;
  const int rr = lane & 15, hi = lane >> 4;
  fx4 acc[4][4] = {};
  for (int k0 = 0; k0 < K; k0 += 64) {
    __syncthreads();
#pragma unroll
    for (int i = 0; i < 4; ++i) {
      int idx = i * 256 + tid;
      int r = idx >> 3, cs = (idx & 7) ^ (r & 7);
      gld16(A + (size_t)(m0 + r) * K + k0 + cs * 8, As + idx * 16);
      gld16(W + (size_t)(n0 + r) * K + k0 + cs * 8, Ws + idx * 16);
    }
    __syncthreads();   // drains DMA
#pragma unroll
    for (int kh = 0; kh < 2; ++kh) {
      bfx8 a[4], b[4];
      const int cg = kh * 4 + hi;
#pragma unroll
      for (int mi = 0; mi < 4; ++mi) {
        int ra = wm * 64 + mi * 16 + rr;
        a[mi] = *(const bfx8*)(As + ra * 128 + ((cg ^ (ra & 7)) << 4));
      }
#pragma unroll
      for (int ni = 0; ni < 4; ++ni) {
        int rb = wn * 64 + ni * 16 + rr;
        b[ni] = *(const bfx8*)(Ws + rb * 128 + ((cg ^ (rb & 7)) << 4));
      }
#pragma unroll
      for (int mi = 0; mi < 4; ++mi)
#pragma unroll
        for (int ni = 0; ni < 4; ++ni)
          acc[mi][ni] = mfma16(a[mi], b[ni], acc[mi][ni]);
    }
  }
  const int cr = hi * 4, cc = rr;
#pragma unroll
  for (int mi = 0; mi < 4; ++mi)
#pragma unroll
    for (int ni = 0; ni < 4; ++ni) {
      int col = n0 + wn * 64 + ni * 16 + cc;
#pragma unroll
      for (int r = 0; r < 4; ++r) {
        int row = m0 + wm * 64 + mi * 16 + cr + r;
        float v = acc[mi][ni][r] + bias[col];
        if (epi == 1) v = leaky_tanh_(v);
        if (wt) stc2((unsigned short*)outB + ((size_t)row * N + col), bf16bits(v));
        else    outB[(size_t)row * N + col] = (__bf16)v;
      }
    }
}

// ---- standalone GEMM (prologue) ----
__launch_bounds__(256)
__global__ void k_gemm(const __bf16* __restrict__ A, const __bf16* __restrict__ W,
                       __bf16* __restrict__ outB, const float* __restrict__ bias,
                       int M, int N, int K, int epi)
{
  __shared__ __align__(16) char sm[32768];
  (void)M;
  gemm_tile(sm, A, W, outB, bias, blockIdx.y * 128, blockIdx.x * 128, N, K, epi, 0);
}

// ---- LDS stage helper (XOR-swizzled 16B chunks), plain cached loads ----
DEV void stage(char* dst, int rsB, const __bf16* __restrict__ src, size_t sStride,
               int n, int lg) {
  for (int idx = threadIdx.x; idx < n; idx += 256) {
    int r = idx >> lg, c = idx & ((1 << lg) - 1);
    *(bfx8*)(dst + r * rsB + ((c * 16) ^ ((r & 7) << 4))) =
        *(const bfx8*)(src + (size_t)r * sStride + c * 8);
  }
}

// ---- fused persistent kernel params ----
struct KP {
  const __bf16 *W2, *whh2b;
  const __bf16 *g1rd;  __bf16 *g1wr;
  const __bf16 *xcrd;  __bf16 *xcwr;
  const __bf16 *infc1;
  const __bf16 *h1rd;  const __bf16 *h1s0;  __bf16 *h1wr;
  __bf16 *x2c; __bf16 *g2;
  const __bf16 *wfc1, *wih1, *wfc2, *wih2;
  const float *bfc1, *bs1, *bfc2, *bs2;
  float *c1, *c2;
  __bf16 *h2a;
  int *cnt;
  int Tc, t2base, do_l1, do_l2, do_fc2, do_ih1, do_fc1;
};

// grid 256: [0,64) LSTM1(chunk k) | [64,80) LSTM2(chunk k-1) | [80,256) workers
// counters (zeroed per launch): cnt[0/128/256/384] h1 (16 adds/line/step);
//  cnt[512] h2 (16/step); cnt[576] fc2-done (NW); cnt[640] ih2-done (NW)
__launch_bounds__(256, 1)
__global__ void k_persist3(KP p)
{
  __shared__ __align__(16) char smem[131072];
  const int tid = threadIdx.x, lane = tid & 63, wv = tid >> 6;
  const int rr = lane & 15, hi = lane >> 4;
  const int col = tid & 15, brow = tid >> 4;
  const int bid = blockIdx.x;
  int* cnt = p.cnt;
  const int Tc = p.Tc;

  if (bid < 64) {
    // ======== LSTM1 (round-5/6/8 proven core) ========
    if (!p.do_l1) return;
    const int ng = bid;
    char* As = smem;
    float* Cp = (float*)smem;

    bfx8 wreg[4][8];
#pragma unroll
    for (int g = 0; g < 4; ++g)
#pragma unroll
      for (int j = 0; j < 8; ++j)
        wreg[g][j] = *(const bfx8*)(p.W2 + (size_t)((ng * 4 + g) * 32 + wv * 8 + j) * 512 + lane * 8);

    float pc[4];
#pragma unroll
    for (int q = 0; q < 4; ++q)
      pc[q] = p.c1[(brow + q * 16) * 1024 + ng * 16 + col];

    for (int s = 0; s < Tc; ++s) {
      float pg[4][4];
#pragma unroll
      for (int q = 0; q < 4; ++q)
#pragma unroll
        for (int g = 0; g < 4; ++g)
          pg[q][g] = (float)p.g1rd[(size_t)(s * 64 + brow + q * 16) * 4096 + g * 1024 + ng * 16 + col];

      if (s > 0 && tid < 4) spin_ge(cnt + tid * 128, 16 * s);
      __syncthreads();

      const __bf16* h1s = (s == 0) ? p.h1s0 : (p.h1wr + (size_t)s * 65536);
      {
        char* dstb = smem + wv * 32768;
#pragma unroll 8
        for (int i = 0; i < 32; ++i) {
          int d = wv * 2048 + i * 64 + lane;
          int r = d >> 7;
          int sg = (r << 7) | ((d & 127) ^ (r & 7));
          gld16c(h1s + (size_t)sg * 8, dstb + i * 1024);
        }
      }
      __syncthreads();

      fx4 acc[4][4] = {};
#pragma unroll
      for (int j = 0; j < 8; ++j) {
        const int kB = (wv * 8 + j) * 64 + hi * 16;
        bfx8 a[4];
#pragma unroll
        for (int m = 0; m < 4; ++m) {
          int ra = m * 16 + rr;
          a[m] = *(const bfx8*)(As + ra * 2048 + (kB ^ ((ra & 7) << 4)));
        }
#pragma unroll
        for (int g = 0; g < 4; ++g)
#pragma unroll
          for (int m = 0; m < 4; ++m)
            acc[g][m] = mfma16(a[m], wreg[g][j], acc[g][m]);
      }
      __syncthreads();
#pragma unroll
      for (int g = 0; g < 4; ++g)
#pragma unroll
        for (int m = 0; m < 4; ++m) {
          int gc = g * 16 + rr;
          int bx = (m * 16 + hi * 4) ^ ((gc & 15) << 2);
          *(fx4*)(Cp + ((wv * 64 + gc) * 64 + bx)) = acc[g][m];
        }
      __syncthreads();

      __bf16* h1o = p.h1wr + (size_t)(s + 1) * 65536;
#pragma unroll
      for (int q = 0; q < 4; ++q) {
        int b_ = brow + q * 16;
        float gv[4];
#pragma unroll
        for (int g = 0; g < 4; ++g) {
          int gc = g * 16 + col;
          int bx = b_ ^ ((gc & 15) << 2);
          float v = pg[q][g];
#pragma unroll
          for (int w = 0; w < 4; ++w)
            v += Cp[(w * 64 + gc) * 64 + bx];
          gv[g] = v;
        }
        float cn = fast_sig(gv[1]) * pc[q] + fast_sig(gv[0]) * fast_tanh(gv[2]);
        pc[q] = cn;
        float hv = fast_sig(gv[3]) * fast_tanh(cn);
        stc2((unsigned short*)h1o + (b_ * 1024 + ng * 16 + col), bf16bits(hv));
      }
      __syncthreads();
      if (tid == 0) arrive1(cnt + (ng & 3) * 128);
    }
#pragma unroll
    for (int q = 0; q < 4; ++q)
      p.c1[(brow + q * 16) * 1024 + ng * 16 + col] = pc[q];

  } else if (bid < 80) {
    // ======== LSTM2 (chunk k-1) ========
    if (!p.do_l2) return;
    const int ng2 = bid - 64;
    char* Ws2 = smem;
    char* As2 = smem + 32768;
    float (*Gx2)[64][16] = (float (*)[64][16])(smem + 32768);

    for (int idx = tid; idx < 2048; idx += 256) {
      int r = idx >> 5, c = idx & 31;
      int wr = (r >> 4) * 256 + ng2 * 16 + (r & 15);
      *(bfx8*)(Ws2 + r * 512 + ((c * 16) ^ ((r & 7) << 4))) =
          *(const bfx8*)(p.whh2b + (size_t)wr * 256 + c * 8);
    }
    float pc2[4];
#pragma unroll
    for (int q = 0; q < 4; ++q)
      pc2[q] = p.c2[(brow + q * 16) * 256 + ng2 * 16 + col];

    // wait until workers finished ih2 (G2 ready, write-through + released)
    if (tid == 0) spin_ge(cnt + 640, NW);
    __syncthreads();

    for (int s = 0; s < Tc; ++s) {
      float pg[4][4];
#pragma unroll
      for (int q = 0; q < 4; ++q)
#pragma unroll
        for (int g = 0; g < 4; ++g)
          pg[q][g] = (float)p.g2[(size_t)(s * 64 + brow + q * 16) * 1024 + g * 256 + ng2 * 16 + col];

      if (s > 0 && tid == 0) spin_ge(cnt + 512, 16 * s);
      __syncthreads();

      const __bf16* h2s = p.h2a + (size_t)(p.t2base + s) * 16384;
      for (int idx = tid; idx < 2048; idx += 256) {
        int r = idx >> 5, c = idx & 31;
        const char* sp = (const char*)(h2s + r * 256 + c * 8);
        unsigned long long lo = ldc8(sp), hi8 = ldc8(sp + 8);
        char* dp = As2 + r * 512 + ((c * 16) ^ ((r & 7) << 4));
        *(unsigned long long*)dp = lo;
        *(unsigned long long*)(dp + 8) = hi8;
      }
      __syncthreads();

      fx4 acc[4] = {};
#pragma unroll
      for (int ks = 0; ks < 8; ++ks) {
        const int cb = ks * 64 + hi * 16;
        int rb = wv * 16 + rr;
        bfx8 bfr = *(const bfx8*)(Ws2 + rb * 512 + (cb ^ ((rb & 7) << 4)));
#pragma unroll
        for (int m = 0; m < 4; ++m) {
          int ra = m * 16 + rr;
          bfx8 afr = *(const bfx8*)(As2 + ra * 512 + (cb ^ ((ra & 7) << 4)));
          acc[m] = mfma16(afr, bfr, acc[m]);
        }
      }
      __syncthreads();
#pragma unroll
      for (int m = 0; m < 4; ++m)
#pragma unroll
        for (int r = 0; r < 4; ++r)
          Gx2[wv][m * 16 + hi * 4 + r][rr] = acc[m][r];
      __syncthreads();

      __bf16* h2o = p.h2a + (size_t)(p.t2base + s + 1) * 16384;
#pragma unroll
      for (int q = 0; q < 4; ++q) {
        int b_ = brow + q * 16;
        float gi = Gx2[0][b_][col] + pg[q][0];
        float gf = Gx2[1][b_][col] + pg[q][1];
        float gg = Gx2[2][b_][col] + pg[q][2];
        float go = Gx2[3][b_][col] + pg[q][3];
        float cn = fast_sig(gf) * pc2[q] + fast_sig(gi) * fast_tanh(gg);
        pc2[q] = cn;
        float hv = fast_sig(go) * fast_tanh(cn);
        stc2((unsigned short*)h2o + (b_ * 256 + ng2 * 16 + col), bf16bits(hv));
      }
      __syncthreads();
      if (tid == 0) arrive1(cnt + 512);
    }
#pragma unroll
    for (int q = 0; q < 4; ++q)
      p.c2[(brow + q * 16) * 256 + ng2 * 16 + col] = pc2[q];

  } else {
    // ======== workers ========
    const int wid = bid - 80;
    const int Mt = (Tc * 64) / 128;
    if (p.do_fc2) {
      // fc2(k-1): x2 = leaky(h1 @ wfc2^T + b)   [h1 from last launch, plain]
      for (int i = wid; i < Mt * 4; i += NW)
        gemm_tile(smem, p.h1rd + 65536, p.wfc2, p.x2c, p.bfc2,
                  (i >> 2) * 128, (i & 3) * 128, F2_, H1_, 1, 1);
      __syncthreads();
      if (tid == 0) { arrive1(cnt + 576); spin_ge(cnt + 576, NW); }
      __syncthreads();
      // ih2(k-1): G2 = x2 @ wih2^T + bs2   [x2 same-launch write-through]
      for (int i = wid; i < Mt * 8; i += NW)
        gemm_tile(smem, p.x2c, p.wih2, p.g2, p.bs2,
                  (i >> 3) * 128, (i & 7) * 128, G2N, F2_, 0, 1);
      __syncthreads();
      if (tid == 0) arrive1(cnt + 640);
    }
    if (p.do_ih1) {
      // ih1(k+1): G1 = Xc @ wih1^T + bs1   [Xc from last launch, plain]
      for (int i = wid; i < Mt * 32; i += NW)
        gemm_tile(smem, p.xcrd, p.wih1, p.g1wr, p.bs1,
                  (i >> 5) * 128, (i & 31) * 128, G1N, H_, 0, 0);
    }
    if (p.do_fc1) {
      // fc1(k+2): Xc = leaky(in @ wfc1^T + b)
      for (int i = wid; i < Mt * 16; i += NW)
        gemm_tile(smem, p.infc1, p.wfc1, p.xcwr, p.bfc1,
                  (i >> 4) * 128, (i & 15) * 128, H_, I_, 1, 0);
    }
  }
}

// ---- fc3 over all timesteps ----
__launch_bounds__(256)
__global__ void k_fc3b(const __bf16* __restrict__ H2mat, const __bf16* __restrict__ w3,
                       const float* __restrict__ b3, float* __restrict__ out)
{
  __shared__ __align__(16) char smem[65536];
  const int tid = threadIdx.x, lane = tid & 63, wv = tid >> 6;
  const int rr = lane & 15, hi = lane >> 4;
  char* As = smem;
  char* Ws = smem + 32768;
  const size_t row0 = (size_t)blockIdx.x * 64;
  stage(As, 512, H2mat + row0 * 256, 256, 2048, 5);
  stage(Ws, 512, w3, 256, 2048, 5);
  __syncthreads();
  fx4 acc[4] = {};
#pragma unroll
  for (int ks = 0; ks < 8; ++ks) {
    const int cbB = ks * 64 + hi * 16;
    int rb = wv * 16 + rr;
    bfx8 bfr = *(const bfx8*)(Ws + rb * 512 + (cbB ^ ((rb & 7) << 4)));
#pragma unroll
    for (int m = 0; m < 4; ++m) {
      int ra = m * 16 + rr;
      bfx8 afr = *(const bfx8*)(As + ra * 512 + (cbB ^ ((ra & 7) << 4)));
      acc[m] = mfma16(afr, bfr, acc[m]);
    }
  }
  float bv = b3[wv * 16 + rr];
#pragma unroll
  for (int m = 0; m < 4; ++m)
#pragma unroll
    for (int r = 0; r < 4; ++r)
      out[(row0 + m * 16 + hi * 4 + r) * 64 + wv * 16 + rr] = acc[m][r] + bv;
}

// ---------------- host launcher ----------------
extern "C" void kernel_launch(void* const* d_in, const int* in_sizes, int n_in,
                              void* d_out, int out_size, void* d_ws, size_t ws_size,
                              hipStream_t stream)
{
  (void)in_sizes; (void)n_in; (void)out_size;
  const float* f_in = (const float*)d_in[0];
  const float* fc1w = (const float*)d_in[1];
  const float* fc1b = (const float*)d_in[2];
  const float* wih1 = (const float*)d_in[3];
  const float* whh1 = (const float*)d_in[4];
  const float* bih1 = (const float*)d_in[5];
  const float* bhh1 = (const float*)d_in[6];
  const float* fc2w = (const float*)d_in[7];
  const float* fc2b = (const float*)d_in[8];
  const float* wih2 = (const float*)d_in[9];
  const float* whh2 = (const float*)d_in[10];
  const float* bih2 = (const float*)d_in[11];
  const float* bhh2 = (const float*)d_in[12];
  const float* fc3w = (const float*)d_in[13];
  const float* fc3b = (const float*)d_in[14];
  float* out = (float*)d_out;

  char* base = (char*)d_ws;
  size_t off = 0;
  auto alloc = [&](size_t bytes) -> char* {
    char* q = base + off;
    off = (off + bytes + 255) & ~(size_t)255;
    return q;
  };
  // fixed region
  __bf16* wb_fc1 = (__bf16*)alloc((size_t)H_ * I_ * 2);
  __bf16* wb_ih1 = (__bf16*)alloc((size_t)G1N * H_ * 2);
  __bf16* W2     = (__bf16*)alloc((size_t)G1N * H1_ * 2);
  __bf16* wb_fc2 = (__bf16*)alloc((size_t)F2_ * H1_ * 2);
  __bf16* wb_ih2 = (__bf16*)alloc((size_t)G2N * F2_ * 2);
  __bf16* wb_hh2 = (__bf16*)alloc((size_t)G2N * H2_ * 2);
  __bf16* wb_fc3 = (__bf16*)alloc((size_t)O_ * H2_ * 2);
  __bf16* in_bf  = (__bf16*)alloc((size_t)T_ * B_ * I_ * 2);
  float*  bsum1  = (float*) alloc((size_t)G1N * 4);
  float*  bsum2  = (float*) alloc((size_t)G2N * 4);
  float*  c1     = (float*) alloc((size_t)B_ * H1_ * 4);
  float*  c2     = (float*) alloc((size_t)B_ * H2_ * 4);
  __bf16* h2a    = (__bf16*)alloc((size_t)(T_ + 1) * B_ * H2_ * 2);
  __bf16* h1zero = (__bf16*)alloc((size_t)B_ * H1_ * 2);
  int*    cnt    = (int*)   alloc(4096);
  size_t fixed = off;

  auto perTc = [](size_t Tc) -> size_t {
    size_t Mc = Tc * 64;
    return 2 * Mc * H_ * 2      // Xc A/B
         + 2 * Mc * G1N * 2     // G1 A/B (bf16)
         + 2 * (Tc + 1) * (size_t)B_ * H1_ * 2   // h1 rings
         + Mc * F2_ * 2         // x2c
         + Mc * G2N * 2         // G2 (bf16)
         + 10 * 256;
  };
  int Tc = 128;
  while (Tc > 8 && fixed + perTc(Tc) > ws_size) Tc >>= 1;
  const int Mc = Tc * 64;
  __bf16* XcA  = (__bf16*)alloc((size_t)Mc * H_ * 2);
  __bf16* XcB  = (__bf16*)alloc((size_t)Mc * H_ * 2);
  __bf16* G1A  = (__bf16*)alloc((size_t)Mc * G1N * 2);
  __bf16* G1B  = (__bf16*)alloc((size_t)Mc * G1N * 2);
  __bf16* h1rA = (__bf16*)alloc((size_t)(Tc + 1) * B_ * H1_ * 2);
  __bf16* h1rB = (__bf16*)alloc((size_t)(Tc + 1) * B_ * H1_ * 2);
  __bf16* x2c  = (__bf16*)alloc((size_t)Mc * F2_ * 2);
  __bf16* G2cb = (__bf16*)alloc((size_t)Mc * G2N * 2);

  // ---- launch 1: prep (conversions + rearrange + zero) ----
  PP q;
  q.fc1w = fc1w; q.wih1f = wih1; q.whh1f = whh1; q.fc2w = fc2w;
  q.wih2f = wih2; q.whh2f = whh2; q.fc3w = fc3w; q.fin = f_in;
  q.bih1 = bih1; q.bhh1 = bhh1; q.bih2 = bih2; q.bhh2 = bhh2;
  q.wb_fc1 = wb_fc1; q.wb_ih1 = wb_ih1; q.W2 = W2; q.wb_fc2 = wb_fc2;
  q.wb_ih2 = wb_ih2; q.wb_hh2 = wb_hh2; q.wb_fc3 = wb_fc3; q.in_bf = in_bf;
  q.bsum1 = bsum1; q.bsum2 = bsum2; q.c1 = c1; q.c2 = c2;
  q.h1zero = h1zero; q.h2a = h2a;
  k_prep<<<2560, 256, 0, stream>>>(q);

  const int chunks = T_ / Tc;
  // ---- launch 2: fc1 for chunks 0+1 fused (XcA|XcB contiguous) ----
  k_gemm<<<dim3(H_ / 128, (2 * Mc) / 128), 256, 0, stream>>>(
      in_bf, wb_fc1, XcA, fc1b, 2 * Mc, H_, I_, 1);
  // ---- launch 3: ih1(0) -> G1A ----
  k_gemm<<<dim3(G1N / 128, Mc / 128), 256, 0, stream>>>(
      XcA, wb_ih1, G1A, bsum1, Mc, G1N, H_, 0);

  KP p;
  p.W2 = W2; p.whh2b = wb_hh2;
  p.wfc1 = wb_fc1; p.wih1 = wb_ih1; p.wfc2 = wb_fc2; p.wih2 = wb_ih2;
  p.bfc1 = fc1b; p.bs1 = bsum1; p.bfc2 = fc2b; p.bs2 = bsum2;
  p.c1 = c1; p.c2 = c2; p.h2a = h2a; p.cnt = cnt;
  p.x2c = x2c; p.g2 = G2cb; p.Tc = Tc;

  for (int k = 0; k < chunks; ++k) {
    hipMemsetAsync(cnt, 0, 4096, stream);
    p.g1rd = (k & 1) ? G1B : G1A;
    p.g1wr = (k & 1) ? G1A : G1B;
    p.xcrd = ((k + 1) & 1) ? XcB : XcA;
    p.xcwr = (k & 1) ? XcB : XcA;
    p.infc1 = (k + 2 < chunks) ? (in_bf + (size_t)(k + 2) * Mc * I_) : in_bf;
    p.h1wr = (k & 1) ? h1rB : h1rA;
    p.h1rd = (k & 1) ? h1rA : h1rB;
    p.h1s0 = (k == 0) ? h1zero : (p.h1rd + (size_t)Tc * 65536);
    p.t2base = (k - 1) * Tc;
    p.do_l1 = 1;
    p.do_l2 = (k >= 1);
    p.do_fc2 = (k >= 1);
    p.do_ih1 = (k + 1 < chunks);
    p.do_fc1 = (k + 2 < chunks);
    k_persist3<<<256, 256, 0, stream>>>(p);
  }
  // tail: fc2/ih2(chunks-1) + LSTM2(chunks-1)
  hipMemsetAsync(cnt, 0, 4096, stream);
  p.h1rd = ((chunks - 1) & 1) ? h1rB : h1rA;
  p.h1wr = (p.h1rd == h1rA) ? h1rB : h1rA;   // unused
  p.h1s0 = h1zero;                            // unused
  p.g1rd = G1A; p.g1wr = G1B; p.xcrd = XcA; p.xcwr = XcB; p.infc1 = in_bf;  // unused
  p.t2base = (chunks - 1) * Tc;
  p.do_l1 = 0; p.do_l2 = 1; p.do_fc2 = 1; p.do_ih1 = 0; p.do_fc1 = 0;
  k_persist3<<<256, 256, 0, stream>>>(p);
  // fc3 over all t
  k_fc3b<<<(T_ * B_) / 64, 256, 0, stream>>>(h2a + (size_t)B_ * H2_, wb_fc3, fc3b, out);
}